// Round 10
// baseline (354.994 us; speedup 1.0000x reference)
//
#include <hip/hip_runtime.h>
#include <math.h>

typedef __bf16 bf16_t;
typedef __bf16 bf16x8 __attribute__((ext_vector_type(8)));
typedef __bf16 bf16x4 __attribute__((ext_vector_type(4)));
typedef float  f32x4  __attribute__((ext_vector_type(4)));

#define NHEAD 16
#define HDIM 64
#define DMODEL 1024
#define TSEQ 2048

#define SBAR() __builtin_amdgcn_s_barrier()
#define LGKM0() do { asm volatile("s_waitcnt lgkmcnt(0)" ::: "memory"); \
                     __builtin_amdgcn_sched_barrier(0); } while (0)

__device__ __forceinline__ f32x4 mfma16(bf16x8 a, bf16x8 b, f32x4 c) {
  return __builtin_amdgcn_mfma_f32_16x16x32_bf16(a, b, c, 0, 0, 0);
}

// async global->LDS, 16B per lane; lds base wave-uniform (HW adds lane*16)
__device__ __forceinline__ void gload16(const bf16_t* g, bf16_t* l) {
  __builtin_amdgcn_global_load_lds((const __attribute__((address_space(1))) void*)g,
                                   (__attribute__((address_space(3))) void*)l, 16, 0, 0);
}

// pack two f32 -> (bf16(hi)<<16)|bf16(lo)
__device__ __forceinline__ unsigned pk2(float lo, float hi) {
  unsigned short a = __builtin_bit_cast(unsigned short, (__bf16)lo);
  unsigned short c = __builtin_bit_cast(unsigned short, (__bf16)hi);
  return ((unsigned)c << 16) | a;
}

// split two f32x4 into hi/lo bf16x8 and store to frag-major LDS slot
__device__ __forceinline__ void cvtstore(f32x4 x0, f32x4 x1, bf16_t* dh, bf16_t* dl, int off) {
  bf16x8 hfr, lfr;
#pragma unroll
  for (int j = 0; j < 4; ++j) {
    float v = x0[j];
    __bf16 hb = (__bf16)v;
    hfr[j] = hb; lfr[j] = (__bf16)(v - (float)hb);
    float w = x1[j];
    __bf16 wb = (__bf16)w;
    hfr[4 + j] = wb; lfr[4 + j] = (__bf16)(w - (float)wb);
  }
  *(bf16x8*)(dh + off) = hfr;
  *(bf16x8*)(dl + off) = lfr;
}

// ---------------- bias table: BM[b][q][k] = alpha*copysign(log1p|df|,df) + amask[q][k] (+ -1e30 if kpm) ----------------
__global__ __launch_bounds__(256)
void build_bias(const float* __restrict__ amask, const unsigned char* __restrict__ kpm,
                const float* __restrict__ sf, const float* __restrict__ alpha_p,
                bf16_t* __restrict__ BM) {
  size_t idx = (size_t)blockIdx.x * 256 + threadIdx.x;
  int k8 = (int)(idx & (TSEQ / 8 - 1));
  size_t bq = idx >> 8;
  int b = (int)(bq >> 11);
  int q = (int)(bq & (TSEQ - 1));
  const float sfq = sf[bq];
  const float alpha = *alpha_p;
  const float* sfk = sf + (size_t)b * TSEQ + k8 * 8;
  const float* am  = amask + (size_t)q * TSEQ + k8 * 8;
  const unsigned char* kp = kpm + (size_t)b * TSEQ + k8 * 8;
  bf16x8 o;
#pragma unroll
  for (int j = 0; j < 8; ++j) {
    float df = sfq - sfk[j];
    float v = alpha * copysignf(log1pf(fabsf(df)), df) + am[j];
    if (kp[j]) v = -1.0e30f;
    o[j] = (__bf16)v;
  }
  *(bf16x8*)&BM[idx * 8] = o;
}

// ---------------- GEMM: C = A @ W^T + bias via bf16x3 split MFMA ----------------
// 512 threads (8 waves, 4m x 2n of 32x32 wave-tiles), 128x64 block tile, BK=32.
// MODE 0: f32 out [M][1024]; MODE 1: bf16 hi/lo head layout [b][h][t][d]; MODE 2: V transposed [b][h][d][t]
template<int MODE>
__global__ __launch_bounds__(512)
void gemm_mfma(const float* __restrict__ A, const float* __restrict__ W,
               const float* __restrict__ bias,
               bf16_t* __restrict__ obh, bf16_t* __restrict__ obl,
               float* __restrict__ of) {
  __shared__ bf16_t AH[8 * 512], AL[8 * 512], WH[4 * 512], WL[4 * 512];  // 24 KiB
  const int tid = threadIdx.x;
  const int lane = tid & 63;
  const int a15 = lane & 15, g = lane >> 4;
  const int wv = tid >> 6, wm = wv >> 1, wn = wv & 1;   // 4 m-slices x 2 n-slices
  const int m0 = blockIdx.y * 128, n0 = blockIdx.x * 64;
  f32x4 acc[2][2] = {};

  // A staged by all 512 threads (slot tid of 512); W by tid<256 (slot tid of 256)
  const int t0 = tid >> 6, l0 = tid & 63;
  const float* pA0 = A + (size_t)(m0 + t0 * 16 + (l0 & 15)) * DMODEL + 8 * (l0 >> 4);
  const bool doW = (tid < 256);
  const int sW = tid & 255;
  const int tw = sW >> 6, lw = sW & 63;
  const float* pW = W + (size_t)(n0 + tw * 16 + (lw & 15)) * DMODEL + 8 * (lw >> 4);

  f32x4 rA0a = *(const f32x4*)pA0, rA0b = *(const f32x4*)(pA0 + 4);
  f32x4 rWa = {}, rWb = {};
  if (doW) { rWa = *(const f32x4*)pW; rWb = *(const f32x4*)(pW + 4); }

  for (int k0 = 0; k0 < DMODEL; k0 += 32) {
    SBAR();                          // prior step's LDS reads consumed (raw: no vmem drain)
    cvtstore(rA0a, rA0b, AH, AL, tid * 8);
    if (doW) cvtstore(rWa, rWb, WH, WL, sW * 8);
    __builtin_amdgcn_sched_barrier(0);
    if (k0 + 32 < DMODEL) {          // prefetch next K-step; survives the barriers below
      pA0 += 32;
      rA0a = *(const f32x4*)pA0; rA0b = *(const f32x4*)(pA0 + 4);
      if (doW) { pW += 32; rWa = *(const f32x4*)pW; rWb = *(const f32x4*)(pW + 4); }
    }
    LGKM0();                         // ds_writes committed
    SBAR();

    bf16x8 ah[2], al[2], wh[2], wl[2];
#pragma unroll
    for (int i = 0; i < 2; ++i) {
      ah[i] = *(const bf16x8*)&AH[(wm * 2 + i) * 512 + lane * 8];
      al[i] = *(const bf16x8*)&AL[(wm * 2 + i) * 512 + lane * 8];
      wh[i] = *(const bf16x8*)&WH[(wn * 2 + i) * 512 + lane * 8];
      wl[i] = *(const bf16x8*)&WL[(wn * 2 + i) * 512 + lane * 8];
    }
    __builtin_amdgcn_s_setprio(1);
    if (MODE == 2) {
#pragma unroll
      for (int i = 0; i < 2; ++i)
#pragma unroll
        for (int j = 0; j < 2; ++j) {
          acc[i][j] = mfma16(wh[i], ah[j], acc[i][j]);
          acc[i][j] = mfma16(wh[i], al[j], acc[i][j]);
          acc[i][j] = mfma16(wl[i], ah[j], acc[i][j]);
        }
    } else {
#pragma unroll
      for (int i = 0; i < 2; ++i)
#pragma unroll
        for (int j = 0; j < 2; ++j) {
          acc[i][j] = mfma16(ah[i], wh[j], acc[i][j]);
          acc[i][j] = mfma16(ah[i], wl[j], acc[i][j]);
          acc[i][j] = mfma16(al[i], wh[j], acc[i][j]);
        }
    }
    __builtin_amdgcn_s_setprio(0);
  }

  if (MODE == 0) {
#pragma unroll
    for (int i = 0; i < 2; ++i)
#pragma unroll
      for (int j = 0; j < 2; ++j) {
        int n = n0 + wn * 32 + j * 16 + a15;
        float bs = bias[n];
#pragma unroll
        for (int r = 0; r < 4; ++r) {
          int m = m0 + wm * 32 + i * 16 + 4 * g + r;
          of[(size_t)m * DMODEL + n] = acc[i][j][r] + bs;
        }
      }
  } else if (MODE == 1) {
#pragma unroll
    for (int i = 0; i < 2; ++i)
#pragma unroll
      for (int j = 0; j < 2; ++j) {
        int n = n0 + wn * 32 + j * 16 + a15;
        float bs = bias[n];
        int hh = n >> 6, d = n & 63;
#pragma unroll
        for (int r = 0; r < 4; ++r) {
          int m = m0 + wm * 32 + i * 16 + 4 * g + r;
          int bb = m >> 11, t = m & (TSEQ - 1);
          float v = acc[i][j][r] + bs;
          size_t o = (((size_t)(bb * NHEAD + hh)) * TSEQ + t) * HDIM + d;
          __bf16 hb = (__bf16)v;
          obh[o] = hb;
          obl[o] = (__bf16)(v - (float)hb);
        }
      }
  } else {
    // MODE2: D rows = W subtile (n-dim, i), D cols = A subtile (m-dim, j)
#pragma unroll
    for (int i = 0; i < 2; ++i)
#pragma unroll
      for (int j = 0; j < 2; ++j) {
        int m = m0 + wm * 32 + j * 16 + a15;
        int bb = m >> 11, t = m & (TSEQ - 1);
#pragma unroll
        for (int r = 0; r < 4; ++r) {
          int n = n0 + wn * 32 + i * 16 + 4 * g + r;
          float v = acc[i][j][r] + bias[n];
          int hh = n >> 6, d = n & 63;
          size_t o = (((size_t)(bb * NHEAD + hh)) * HDIM + d) * TSEQ + t;
          __bf16 hb = (__bf16)v;
          obh[o] = hb;
          obl[o] = (__bf16)(v - (float)hb);
        }
      }
  }
}

// ---------------- Flash attention: 4 waves/block, 32 q-rows PER WAVE (2 groups) ----------------
// LDS-BW-bound fix: K/V frags read from LDS once feed BOTH q-groups' MFMAs -> LDS
// traffic per FLOP ~halves. global_load_lds staging (zero staging VGPRs, no spill),
// dbuf + counted vmcnt(8). Bias loaded mid-iter directly into bmv (no bmn copy regs).
__global__ __launch_bounds__(256)
void attn_mfma(const bf16_t* __restrict__ Qhi, const bf16_t* __restrict__ Qlo,
               const bf16_t* __restrict__ Khi, const bf16_t* __restrict__ Klo,
               const bf16_t* __restrict__ Vth, const bf16_t* __restrict__ Vtl,
               const bf16_t* __restrict__ BMt, float* __restrict__ O) {
  __shared__ bf16_t KH[2][8 * 512], KL[2][8 * 512], VH[2][8 * 512], VL[2][8 * 512];  // 64 KiB
  __shared__ bf16_t PS[4 * 2 * 512];   // per-wave x per-group P scratch: 8 KiB  (72 KiB total)
  const int tid = threadIdx.x;
  const int lane = tid & 63, wv = tid >> 6;          // wv = 0..3
  const int a15 = lane & 15, g = lane >> 4;
  const int b = blockIdx.z, h = blockIdx.y, q0 = blockIdx.x * 128;
  const int bh = b * NHEAD + h;
  const int qgA = q0 + wv * 32 + a15;                // group A row; group B = qgA + 16
  constexpr int NT = TSEQ / 64;

  const bf16_t* QhA = Qhi + ((size_t)bh * TSEQ + qgA) * HDIM;
  const bf16_t* QlA = Qlo + ((size_t)bh * TSEQ + qgA) * HDIM;
  const bf16_t* Kh_b = Khi + (size_t)bh * TSEQ * HDIM;
  const bf16_t* Kl_b = Klo + (size_t)bh * TSEQ * HDIM;
  const bf16_t* Vh_b = Vth + (size_t)bh * HDIM * TSEQ;
  const bf16_t* Vl_b = Vtl + (size_t)bh * HDIM * TSEQ;
  const bf16_t* bmA = BMt + ((size_t)b * TSEQ + qgA) * TSEQ;
  const bf16_t* bmB = bmA + (size_t)16 * TSEQ;

  bf16x8 qhA[2], qlA[2], qhB[2], qlB[2];
  qhA[0] = *(const bf16x8*)&QhA[8 * g];
  qhA[1] = *(const bf16x8*)&QhA[32 + 8 * g];
  qlA[0] = *(const bf16x8*)&QlA[8 * g];
  qlA[1] = *(const bf16x8*)&QlA[32 + 8 * g];
  qhB[0] = *(const bf16x8*)&QhA[16 * HDIM + 8 * g];
  qhB[1] = *(const bf16x8*)&QhA[16 * HDIM + 32 + 8 * g];
  qlB[0] = *(const bf16x8*)&QlA[16 * HDIM + 8 * g];
  qlB[1] = *(const bf16x8*)&QlA[16 * HDIM + 32 + 8 * g];

  f32x4 acoA[4] = {}, acoB[4] = {};
  float mA = -3.0e38f, lA = 0.f, mB = -3.0e38f, lB = 0.f;
  bf16x4 bmvA[4], bmvB[4];

  // wave wv stages K rows [16wv,16wv+16) and Vt d-rows [16wv,16wv+16), both 32-col halves
  auto stage = [&](int k0, int buf) {
#pragma unroll
    for (int c = 0; c < 2; ++c) {
      int sb = wv * 2 + c;
      size_t ko = (size_t)(k0 + 16 * wv + a15) * HDIM + 32 * c + 8 * g;
      gload16(Kh_b + ko, &KH[buf][sb * 512]);
      gload16(Kl_b + ko, &KL[buf][sb * 512]);
      size_t vo = (size_t)(16 * wv + a15) * TSEQ + k0 + 32 * c + 8 * g;
      gload16(Vh_b + vo, &VH[buf][sb * 512]);
      gload16(Vl_b + vo, &VL[buf][sb * 512]);
    }
  };

  // prologue: bias tile 0 (8 loads) + K/V tile 0 (8 loads)
#pragma unroll
  for (int mt = 0; mt < 4; ++mt) {
    bmvA[mt] = *(const bf16x4*)&bmA[16 * mt + 4 * g];
    bmvB[mt] = *(const bf16x4*)&bmB[16 * mt + 4 * g];
  }
  stage(0, 0);

  const int psbA = (wv * 2 + 0) * 512 + a15 * 32;
  const int psbB = (wv * 2 + 1) * 512 + a15 * 32;
  const int r3 = a15 & 3;

  for (int t = 0; t < NT; ++t) {
    const int cur = t & 1;
    if (t + 1 < NT) {
      stage((t + 1) * 64, cur ^ 1);                    // 8 gloads for t+1, stay in flight
      asm volatile("s_waitcnt vmcnt(8)" ::: "memory"); // drain tile t's loads only
    } else {
      asm volatile("s_waitcnt vmcnt(0)" ::: "memory");
    }
    __builtin_amdgcn_sched_barrier(0);
    SBAR();                          // tile t's LDS data visible to all waves

    // --- S^T = K·Q for both q-groups; K frags read ONCE ---
    f32x4 s4a[4], s4b[4];
    __builtin_amdgcn_s_setprio(1);
#pragma unroll
    for (int mt = 0; mt < 4; ++mt) {
      bf16x8 k0h = *(const bf16x8*)&KH[cur][(mt * 2 + 0) * 512 + lane * 8];
      bf16x8 k1h = *(const bf16x8*)&KH[cur][(mt * 2 + 1) * 512 + lane * 8];
      bf16x8 k0l = *(const bf16x8*)&KL[cur][(mt * 2 + 0) * 512 + lane * 8];
      bf16x8 k1l = *(const bf16x8*)&KL[cur][(mt * 2 + 1) * 512 + lane * 8];
      f32x4 sa = {};
      sa = mfma16(k0h, qhA[0], sa);
      sa = mfma16(k1h, qhA[1], sa);
      sa = mfma16(k0h, qlA[0], sa);
      sa = mfma16(k1h, qlA[1], sa);
      sa = mfma16(k0l, qhA[0], sa);
      sa = mfma16(k1l, qhA[1], sa);
      s4a[mt] = sa;
      f32x4 sb_ = {};
      sb_ = mfma16(k0h, qhB[0], sb_);
      sb_ = mfma16(k1h, qhB[1], sb_);
      sb_ = mfma16(k0h, qlB[0], sb_);
      sb_ = mfma16(k1h, qlB[1], sb_);
      sb_ = mfma16(k0l, qhB[0], sb_);
      sb_ = mfma16(k1l, qhB[1], sb_);
      s4b[mt] = sb_;
    }
    __builtin_amdgcn_s_setprio(0);

    // --- scores + online softmax (group A) ---
#pragma unroll
    for (int mt = 0; mt < 4; ++mt)
#pragma unroll
      for (int r = 0; r < 4; ++r)
        s4a[mt][r] = fmaf(s4a[mt][r], 0.125f, (float)bmvA[mt][r]);
    float tmaxA = -3.0e38f;
#pragma unroll
    for (int mt = 0; mt < 4; ++mt)
#pragma unroll
      for (int r = 0; r < 4; ++r) tmaxA = fmaxf(tmaxA, s4a[mt][r]);
    tmaxA = fmaxf(tmaxA, __shfl_xor(tmaxA, 16));
    tmaxA = fmaxf(tmaxA, __shfl_xor(tmaxA, 32));
    if (!__all(tmaxA - mA <= 8.0f)) {
      float mn = fmaxf(mA, tmaxA);
      float corr = __expf(mA - mn);
      lA *= corr;
#pragma unroll
      for (int dt = 0; dt < 4; ++dt) acoA[dt] *= corr;
      mA = mn;
    }
    float psumA = 0.f;
    unsigned pk01A[4], pk23A[4];
#pragma unroll
    for (int mt = 0; mt < 4; ++mt) {
      float p0 = __expf(s4a[mt][0] - mA);
      float p1 = __expf(s4a[mt][1] - mA);
      float p2 = __expf(s4a[mt][2] - mA);
      float p3 = __expf(s4a[mt][3] - mA);
      psumA += (p0 + p1) + (p2 + p3);
      pk01A[mt] = pk2(p0, p1);
      pk23A[mt] = pk2(p2, p3);
    }
    psumA += __shfl_xor(psumA, 16);
    psumA += __shfl_xor(psumA, 32);
    lA += psumA;

    // --- scores + online softmax (group B) ---
#pragma unroll
    for (int mt = 0; mt < 4; ++mt)
#pragma unroll
      for (int r = 0; r < 4; ++r)
        s4b[mt][r] = fmaf(s4b[mt][r], 0.125f, (float)bmvB[mt][r]);
    float tmaxB = -3.0e38f;
#pragma unroll
    for (int mt = 0; mt < 4; ++mt)
#pragma unroll
      for (int r = 0; r < 4; ++r) tmaxB = fmaxf(tmaxB, s4b[mt][r]);
    tmaxB = fmaxf(tmaxB, __shfl_xor(tmaxB, 16));
    tmaxB = fmaxf(tmaxB, __shfl_xor(tmaxB, 32));
    if (!__all(tmaxB - mB <= 8.0f)) {
      float mn = fmaxf(mB, tmaxB);
      float corr = __expf(mB - mn);
      lB *= corr;
#pragma unroll
      for (int dt = 0; dt < 4; ++dt) acoB[dt] *= corr;
      mB = mn;
    }
    float psumB = 0.f;
    unsigned pk01B[4], pk23B[4];
#pragma unroll
    for (int mt = 0; mt < 4; ++mt) {
      float p0 = __expf(s4b[mt][0] - mB);
      float p1 = __expf(s4b[mt][1] - mB);
      float p2 = __expf(s4b[mt][2] - mB);
      float p3 = __expf(s4b[mt][3] - mB);
      psumB += (p0 + p1) + (p2 + p3);
      pk01B[mt] = pk2(p0, p1);
      pk23B[mt] = pk2(p2, p3);
    }
    psumB += __shfl_xor(psumB, 16);
    psumB += __shfl_xor(psumB, 32);
    lB += psumB;

    // --- bias for tile t+1 (issued here: hides under PV + next QK; counted in vmcnt) ---
    if (t + 1 < NT) {
      const int kn = (t + 1) * 64;
#pragma unroll
      for (int mt = 0; mt < 4; ++mt) {
        bmvA[mt] = *(const bf16x4*)&bmA[kn + 16 * mt + 4 * g];
        bmvB[mt] = *(const bf16x4*)&bmB[kn + 16 * mt + 4 * g];
      }
    }

    // --- P -> B-frag via per-wave swizzled LDS scratch; PV: V frags read ONCE for both groups ---
    __builtin_amdgcn_s_setprio(1);
#pragma unroll
    for (int kss = 0; kss < 2; ++kss) {
#pragma unroll
      for (int mh = 0; mh < 2; ++mh) {
        int mt = kss * 2 + mh;
        int phys = ((mh << 1) | (g >> 1)) ^ r3;
        uint2 wA; wA.x = pk01A[mt]; wA.y = pk23A[mt];
        *(uint2*)&PS[psbA + phys * 8 + (g & 1) * 4] = wA;
        uint2 wB; wB.x = pk01B[mt]; wB.y = pk23B[mt];
        *(uint2*)&PS[psbB + phys * 8 + (g & 1) * 4] = wB;
      }
      LGKM0();                        // intra-wave: writes visible to own lanes
      bf16x8 pfA = *(const bf16x8*)&PS[psbA + ((g ^ r3) << 3)];
      bf16x8 pfB = *(const bf16x8*)&PS[psbB + ((g ^ r3) << 3)];
#pragma unroll
      for (int dt = 0; dt < 4; ++dt) {
        bf16x8 vh = *(const bf16x8*)&VH[cur][(dt * 2 + kss) * 512 + lane * 8];
        bf16x8 vl = *(const bf16x8*)&VL[cur][(dt * 2 + kss) * 512 + lane * 8];
        acoA[dt] = mfma16(vh, pfA, acoA[dt]);
        acoA[dt] = mfma16(vl, pfA, acoA[dt]);
        acoB[dt] = mfma16(vh, pfB, acoB[dt]);
        acoB[dt] = mfma16(vl, pfB, acoB[dt]);
      }
    }
    __builtin_amdgcn_s_setprio(0);

    SBAR();   // all waves done reading buf `cur` before next iter's stage overwrites it
  }

  float invA = 1.0f / lA, invB = 1.0f / lB;
#pragma unroll
  for (int dt = 0; dt < 4; ++dt) {
    f32x4 oA = acoA[dt] * invA;
    *(f32x4*)&O[((size_t)b * TSEQ + qgA) * DMODEL + h * HDIM + dt * 16 + 4 * g] = oA;
    f32x4 oB = acoB[dt] * invB;
    *(f32x4*)&O[((size_t)b * TSEQ + qgA + 16) * DMODEL + h * HDIM + dt * 16 + 4 * g] = oB;
  }
}

extern "C" void kernel_launch(void* const* d_in, const int* in_sizes, int n_in,
                              void* d_out, int out_size, void* d_ws, size_t ws_size,
                              hipStream_t stream) {
  const float* query = (const float*)d_in[0];
  const float* key = (const float*)d_in[1];
  const float* value = (const float*)d_in[2];
  const unsigned char* kpm = (const unsigned char*)d_in[3];
  const float* amask = (const float*)d_in[4];
  const float* sf = (const float*)d_in[5];
  const float* Wq = (const float*)d_in[6];
  const float* bq = (const float*)d_in[7];
  const float* Wk = (const float*)d_in[8];
  const float* bk = (const float*)d_in[9];
  const float* Wv = (const float*)d_in[10];
  const float* bv = (const float*)d_in[11];
  const float* Wo = (const float*)d_in[12];
  const float* bo = (const float*)d_in[13];
  const float* alpha = (const float*)d_in[14];
  float* out = (float*)d_out;

  const size_t NEL = (size_t)2 * NHEAD * TSEQ * HDIM;  // 4,194,304 per bf16 array
  bf16_t* p = (bf16_t*)d_ws;
  bf16_t* Qh = p;
  bf16_t* Ql = p + NEL;
  bf16_t* Kh = p + 2 * NEL;
  bf16_t* Kl = p + 3 * NEL;
  bf16_t* Vh = p + 4 * NEL;
  bf16_t* Vl = p + 5 * NEL;
  float* Oa = (float*)(p + 6 * NEL);                    // 16.8 MB
  bf16_t* BMt = (bf16_t*)(Oa + (size_t)4096 * DMODEL);  // 16.8 MB  (total 80 MiB)

  build_bias<<<dim3(4096), dim3(256), 0, stream>>>(amask, kpm, sf, alpha, BMt);

  dim3 gg(16, 32), gb(512);
  gemm_mfma<1><<<gg, gb, 0, stream>>>(query, Wq, bq, Qh, Ql, nullptr);
  gemm_mfma<1><<<gg, gb, 0, stream>>>(key, Wk, bk, Kh, Kl, nullptr);
  gemm_mfma<2><<<gg, gb, 0, stream>>>(value, Wv, bv, Vh, Vl, nullptr);
  dim3 ga(TSEQ / 128, NHEAD, 2);   // (16, 16, 2) = 512 blocks, 256 thr (4 waves x 32 q)
  attn_mfma<<<ga, dim3(256), 0, stream>>>(Qh, Ql, Kh, Kl, Vh, Vl, BMt, Oa);
  gemm_mfma<0><<<gg, gb, 0, stream>>>(Oa, Wo, bo, nullptr, nullptr, out);
}

// Round 11
// 347.205 us; speedup vs baseline: 1.0224x; 1.0224x over previous
//
#include <hip/hip_runtime.h>
#include <math.h>

typedef __bf16 bf16_t;
typedef __bf16 bf16x8 __attribute__((ext_vector_type(8)));
typedef __bf16 bf16x4 __attribute__((ext_vector_type(4)));
typedef float  f32x4  __attribute__((ext_vector_type(4)));

#define NHEAD 16
#define HDIM 64
#define DMODEL 1024
#define TSEQ 2048
#define WEL (DMODEL * DMODEL)

#define SBAR() __builtin_amdgcn_s_barrier()
#define SCHED0() __builtin_amdgcn_sched_barrier(0)
#define LGKM0() do { asm volatile("s_waitcnt lgkmcnt(0)" ::: "memory"); \
                     __builtin_amdgcn_sched_barrier(0); } while (0)

__device__ __forceinline__ f32x4 mfma16(bf16x8 a, bf16x8 b, f32x4 c) {
  return __builtin_amdgcn_mfma_f32_16x16x32_bf16(a, b, c, 0, 0, 0);
}

// async global->LDS, 16B per lane; lds base wave-uniform (HW adds lane*16)
__device__ __forceinline__ void gload16(const bf16_t* g, bf16_t* l) {
  __builtin_amdgcn_global_load_lds((const __attribute__((address_space(1))) void*)g,
                                   (__attribute__((address_space(3))) void*)l, 16, 0, 0);
}

__device__ __forceinline__ unsigned pk2(float lo, float hi) {
  unsigned short a = __builtin_bit_cast(unsigned short, (__bf16)lo);
  unsigned short c = __builtin_bit_cast(unsigned short, (__bf16)hi);
  return ((unsigned)c << 16) | a;
}

// split two f32x4 into hi/lo bf16x8 and store to frag-major LDS slot
__device__ __forceinline__ void cvtstore(f32x4 x0, f32x4 x1, bf16_t* dh, bf16_t* dl, int off) {
  bf16x8 hfr, lfr;
#pragma unroll
  for (int j = 0; j < 4; ++j) {
    float v = x0[j];
    __bf16 hb = (__bf16)v;
    hfr[j] = hb; lfr[j] = (__bf16)(v - (float)hb);
    float w = x1[j];
    __bf16 wb = (__bf16)w;
    hfr[4 + j] = wb; lfr[4 + j] = (__bf16)(w - (float)wb);
  }
  *(bf16x8*)(dh + off) = hfr;
  *(bf16x8*)(dl + off) = lfr;
}

// ---------------- presplit 4 weight matrices -> hi/lo bf16 (one-time, memory-bound) ----------------
__global__ __launch_bounds__(256)
void presplit_w(const float* __restrict__ w0, const float* __restrict__ w1,
                const float* __restrict__ w2, const float* __restrict__ w3,
                bf16_t* __restrict__ out) {
  const int y = blockIdx.y;
  const float* src = (y == 0) ? w0 : (y == 1) ? w1 : (y == 2) ? w2 : w3;
  size_t i = ((size_t)blockIdx.x * 256 + threadIdx.x) * 8;
  f32x4 a = *(const f32x4*)(src + i);
  f32x4 c = *(const f32x4*)(src + i + 4);
  bf16x8 h, l;
#pragma unroll
  for (int j = 0; j < 4; ++j) {
    __bf16 hb = (__bf16)a[j];
    h[j] = hb; l[j] = (__bf16)(a[j] - (float)hb);
    __bf16 cb = (__bf16)c[j];
    h[4 + j] = cb; l[4 + j] = (__bf16)(c[j] - (float)cb);
  }
  bf16_t* dh = out + (size_t)y * 2 * WEL;
  *(bf16x8*)(dh + i) = h;
  *(bf16x8*)(dh + WEL + i) = l;
}

// ---------------- bias table ----------------
__global__ __launch_bounds__(256)
void build_bias(const float* __restrict__ amask, const unsigned char* __restrict__ kpm,
                const float* __restrict__ sf, const float* __restrict__ alpha_p,
                bf16_t* __restrict__ BM) {
  size_t idx = (size_t)blockIdx.x * 256 + threadIdx.x;
  int k8 = (int)(idx & (TSEQ / 8 - 1));
  size_t bq = idx >> 8;
  int b = (int)(bq >> 11);
  int q = (int)(bq & (TSEQ - 1));
  const float sfq = sf[bq];
  const float alpha = *alpha_p;
  const float* sfk = sf + (size_t)b * TSEQ + k8 * 8;
  const float* am  = amask + (size_t)q * TSEQ + k8 * 8;
  const unsigned char* kp = kpm + (size_t)b * TSEQ + k8 * 8;
  bf16x8 o;
#pragma unroll
  for (int j = 0; j < 8; ++j) {
    float df = sfq - sfk[j];
    float v = alpha * copysignf(log1pf(fabsf(df)), df) + am[j];
    if (kp[j]) v = -1.0e30f;
    o[j] = (__bf16)v;
  }
  *(bf16x8*)&BM[idx * 8] = o;
}

// ---------------- QKV projection: A f32 (in-kernel split), W pre-split via gload16 ----------------
// 512 thr (8 waves, 4m x 2n of 32x32), tile 128x64, BK=32. W LDS double-buffered,
// counted vmcnt keeps W stage + A reg-prefetch in flight across barriers.
// MODE 1: head layout [b][h][t][d]; MODE 2: V transposed [b][h][d][t]
template<int MODE>
__global__ __launch_bounds__(512)
void gemm_qkv(const float* __restrict__ A, const bf16_t* __restrict__ Wh,
              const bf16_t* __restrict__ Wl, const float* __restrict__ bias,
              bf16_t* __restrict__ obh, bf16_t* __restrict__ obl) {
  __shared__ bf16_t AH[8 * 512], AL[8 * 512], WHs[2][4 * 512], WLs[2][4 * 512];  // 32 KiB
  const int tid = threadIdx.x;
  const int lane = tid & 63;
  const int a15 = lane & 15, g = lane >> 4;
  const int wv = tid >> 6, wm = wv >> 1, wn = wv & 1;
  const int m0 = blockIdx.y * 128, n0 = blockIdx.x * 64;
  f32x4 acc[2][2] = {};

  const int t0 = tid >> 6, l0 = tid & 63;
  const float* pA = A + (size_t)(m0 + t0 * 16 + (l0 & 15)) * DMODEL + 8 * (l0 >> 4);
  const int wts = wv & 3;
  const bf16_t* pWg = ((wv < 4) ? Wh : Wl) + (size_t)(n0 + wts * 16 + a15) * DMODEL + 8 * g;

  f32x4 rAa = *(const f32x4*)pA, rAb = *(const f32x4*)(pA + 4);
  gload16(pWg, (wv < 4) ? &WHs[0][wts * 512] : &WLs[0][wts * 512]);

  constexpr int NK = DMODEL / 32;
  for (int t = 0; t < NK; ++t) {
    const int cur = t & 1;
    SBAR();                                   // prior step's LDS reads consumed
    cvtstore(rAa, rAb, AH, AL, tid * 8);      // compiler waits rA only; W(t) stays in flight
    SCHED0();
    if (t + 1 < NK) {
      pA += 32;
      rAa = *(const f32x4*)pA; rAb = *(const f32x4*)(pA + 4);   // A prefetch t+1
      SCHED0();
      gload16(pWg + (t + 1) * 32, (wv < 4) ? &WHs[cur ^ 1][wts * 512]
                                           : &WLs[cur ^ 1][wts * 512]);
      SCHED0();
      asm volatile("s_waitcnt vmcnt(3)" ::: "memory");  // drain W(t); keep rA(t+1)x2 + W(t+1)
    } else {
      asm volatile("s_waitcnt vmcnt(0)" ::: "memory");
    }
    LGKM0();                                  // ds_writes committed
    SBAR();

    bf16x8 ah[2], al[2], wh[2], wl[2];
#pragma unroll
    for (int i = 0; i < 2; ++i) {
      ah[i] = *(const bf16x8*)&AH[(wm * 2 + i) * 512 + lane * 8];
      al[i] = *(const bf16x8*)&AL[(wm * 2 + i) * 512 + lane * 8];
      wh[i] = *(const bf16x8*)&WHs[cur][(wn * 2 + i) * 512 + lane * 8];
      wl[i] = *(const bf16x8*)&WLs[cur][(wn * 2 + i) * 512 + lane * 8];
    }
    __builtin_amdgcn_s_setprio(1);
    if (MODE == 2) {
#pragma unroll
      for (int i = 0; i < 2; ++i)
#pragma unroll
        for (int j = 0; j < 2; ++j) {
          acc[i][j] = mfma16(wh[i], ah[j], acc[i][j]);
          acc[i][j] = mfma16(wh[i], al[j], acc[i][j]);
          acc[i][j] = mfma16(wl[i], ah[j], acc[i][j]);
        }
    } else {
#pragma unroll
      for (int i = 0; i < 2; ++i)
#pragma unroll
        for (int j = 0; j < 2; ++j) {
          acc[i][j] = mfma16(ah[i], wh[j], acc[i][j]);
          acc[i][j] = mfma16(ah[i], wl[j], acc[i][j]);
          acc[i][j] = mfma16(al[i], wh[j], acc[i][j]);
        }
    }
    __builtin_amdgcn_s_setprio(0);
  }

  if (MODE == 1) {
#pragma unroll
    for (int i = 0; i < 2; ++i)
#pragma unroll
      for (int j = 0; j < 2; ++j) {
        int n = n0 + wn * 32 + j * 16 + a15;
        float bs = bias[n];
        int hh = n >> 6, d = n & 63;
#pragma unroll
        for (int r = 0; r < 4; ++r) {
          int m = m0 + wm * 32 + i * 16 + 4 * g + r;
          int bb = m >> 11, t = m & (TSEQ - 1);
          float v = acc[i][j][r] + bs;
          size_t o = (((size_t)(bb * NHEAD + hh)) * TSEQ + t) * HDIM + d;
          __bf16 hb = (__bf16)v;
          obh[o] = hb;
          obl[o] = (__bf16)(v - (float)hb);
        }
      }
  } else {
#pragma unroll
    for (int i = 0; i < 2; ++i)
#pragma unroll
      for (int j = 0; j < 2; ++j) {
        int m = m0 + wm * 32 + j * 16 + a15;
        int bb = m >> 11, t = m & (TSEQ - 1);
#pragma unroll
        for (int r = 0; r < 4; ++r) {
          int n = n0 + wn * 32 + i * 16 + 4 * g + r;
          float v = acc[i][j][r] + bias[n];
          int hh = n >> 6, d = n & 63;
          size_t o = (((size_t)(bb * NHEAD + hh)) * HDIM + d) * TSEQ + t;
          __bf16 hb = (__bf16)v;
          obh[o] = hb;
          obl[o] = (__bf16)(v - (float)hb);
        }
      }
  }
}

// ---------------- O projection: A and W both pre-split bf16, pure gload16 dbuf ----------------
__global__ __launch_bounds__(512)
void gemm_out(const bf16_t* __restrict__ Ah, const bf16_t* __restrict__ Al,
              const bf16_t* __restrict__ Wh, const bf16_t* __restrict__ Wl,
              const float* __restrict__ bias, float* __restrict__ of) {
  __shared__ bf16_t AHs[2][8 * 512], ALs[2][8 * 512], WHs[2][4 * 512], WLs[2][4 * 512];  // 48 KiB
  const int tid = threadIdx.x;
  const int lane = tid & 63;
  const int a15 = lane & 15, g = lane >> 4;
  const int wv = tid >> 6, wm = wv >> 1, wn = wv & 1;
  const int m0 = blockIdx.y * 128, n0 = blockIdx.x * 64;
  f32x4 acc[2][2] = {};

  // wave wv stages AH slot wv + AL slot wv; waves 0-3 also WH slot wv, waves 4-7 WL slot wv-4
  const bf16_t* pAh = Ah + (size_t)(m0 + wv * 16 + a15) * DMODEL + 8 * g;
  const bf16_t* pAl = Al + (size_t)(m0 + wv * 16 + a15) * DMODEL + 8 * g;
  const int wts = wv & 3;
  const bf16_t* pWg = ((wv < 4) ? Wh : Wl) + (size_t)(n0 + wts * 16 + a15) * DMODEL + 8 * g;

  auto stage = [&](int t, int buf) {
    gload16(pAh + t * 32, &AHs[buf][wv * 512]);
    gload16(pAl + t * 32, &ALs[buf][wv * 512]);
    gload16(pWg + t * 32, (wv < 4) ? &WHs[buf][wts * 512] : &WLs[buf][wts * 512]);
  };
  stage(0, 0);

  constexpr int NK = DMODEL / 32;
  for (int t = 0; t < NK; ++t) {
    const int cur = t & 1;
    if (t + 1 < NK) {
      stage(t + 1, cur ^ 1);                            // 3 gloads, stay in flight
      asm volatile("s_waitcnt vmcnt(3)" ::: "memory");  // drain tile t's 3 only
    } else {
      asm volatile("s_waitcnt vmcnt(0)" ::: "memory");
    }
    SCHED0();
    SBAR();

    bf16x8 ah[2], al[2], wh[2], wl[2];
#pragma unroll
    for (int i = 0; i < 2; ++i) {
      ah[i] = *(const bf16x8*)&AHs[cur][(wm * 2 + i) * 512 + lane * 8];
      al[i] = *(const bf16x8*)&ALs[cur][(wm * 2 + i) * 512 + lane * 8];
      wh[i] = *(const bf16x8*)&WHs[cur][(wn * 2 + i) * 512 + lane * 8];
      wl[i] = *(const bf16x8*)&WLs[cur][(wn * 2 + i) * 512 + lane * 8];
    }
    __builtin_amdgcn_s_setprio(1);
#pragma unroll
    for (int i = 0; i < 2; ++i)
#pragma unroll
      for (int j = 0; j < 2; ++j) {
        acc[i][j] = mfma16(ah[i], wh[j], acc[i][j]);
        acc[i][j] = mfma16(ah[i], wl[j], acc[i][j]);
        acc[i][j] = mfma16(al[i], wh[j], acc[i][j]);
      }
    __builtin_amdgcn_s_setprio(0);
    SBAR();   // all waves done reading buf cur before next stage overwrites
  }

#pragma unroll
  for (int i = 0; i < 2; ++i)
#pragma unroll
    for (int j = 0; j < 2; ++j) {
      int n = n0 + wn * 32 + j * 16 + a15;
      float bs = bias[n];
#pragma unroll
      for (int r = 0; r < 4; ++r) {
        int m = m0 + wm * 32 + i * 16 + 4 * g + r;
        of[(size_t)m * DMODEL + n] = acc[i][j][r] + bs;
      }
    }
}

// ---------------- Flash attention (R9 config: 8 waves x 16 q-rows), bf16 hi/lo output ----------------
__global__ __launch_bounds__(512)
void attn_mfma(const bf16_t* __restrict__ Qhi, const bf16_t* __restrict__ Qlo,
               const bf16_t* __restrict__ Khi, const bf16_t* __restrict__ Klo,
               const bf16_t* __restrict__ Vth, const bf16_t* __restrict__ Vtl,
               const bf16_t* __restrict__ BMt,
               bf16_t* __restrict__ Oh, bf16_t* __restrict__ Ol) {
  __shared__ bf16_t KH[2][8 * 512], KL[2][8 * 512], VH[2][8 * 512], VL[2][8 * 512];  // 64 KiB
  __shared__ bf16_t PS[8 * 512];     // per-wave P scratch: 8 KiB
  const int tid = threadIdx.x;
  const int lane = tid & 63, wv = tid >> 6;          // wv = 0..7
  const int a15 = lane & 15, g = lane >> 4;
  const int b = blockIdx.z, h = blockIdx.y, q0 = blockIdx.x * 128;
  const int bh = b * NHEAD + h;
  const int qg = q0 + wv * 16 + a15;
  constexpr int NT = TSEQ / 64;

  const bf16_t* Qh_b = Qhi + ((size_t)bh * TSEQ + qg) * HDIM;
  const bf16_t* Ql_b = Qlo + ((size_t)bh * TSEQ + qg) * HDIM;
  const bf16_t* Kh_b = Khi + (size_t)bh * TSEQ * HDIM;
  const bf16_t* Kl_b = Klo + (size_t)bh * TSEQ * HDIM;
  const bf16_t* Vh_b = Vth + (size_t)bh * HDIM * TSEQ;
  const bf16_t* Vl_b = Vtl + (size_t)bh * HDIM * TSEQ;
  const bf16_t* bmrow = BMt + ((size_t)b * TSEQ + qg) * TSEQ;

  bf16x8 qh[2], ql[2];
  qh[0] = *(const bf16x8*)&Qh_b[8 * g];
  qh[1] = *(const bf16x8*)&Qh_b[32 + 8 * g];
  ql[0] = *(const bf16x8*)&Ql_b[8 * g];
  ql[1] = *(const bf16x8*)&Ql_b[32 + 8 * g];

  f32x4 aco[4] = {};
  float m_run = -3.0e38f, l_run = 0.f;
  bf16x4 bmv[4], bmn[4];

  const int ts = wv >> 1, ks = wv & 1;
  auto stage = [&](int k0, int buf) {
    size_t ko = (size_t)(k0 + 16 * ts + a15) * HDIM + 32 * ks + 8 * g;
    gload16(Kh_b + ko, &KH[buf][wv * 512]);
    gload16(Kl_b + ko, &KL[buf][wv * 512]);
    size_t vo = (size_t)(16 * ts + a15) * TSEQ + k0 + 32 * ks + 8 * g;
    gload16(Vh_b + vo, &VH[buf][wv * 512]);
    gload16(Vl_b + vo, &VL[buf][wv * 512]);
  };

#pragma unroll
  for (int mt = 0; mt < 4; ++mt) bmv[mt] = *(const bf16x4*)&bmrow[16 * mt + 4 * g];
  stage(0, 0);

  const int psb = wv * 512 + a15 * 32;
  const int r3 = a15 & 3;

  for (int t = 0; t < NT; ++t) {
    const int cur = t & 1;
    if (t + 1 < NT) {
      const int kn = (t + 1) * 64;
#pragma unroll
      for (int mt = 0; mt < 4; ++mt) bmn[mt] = *(const bf16x4*)&bmrow[kn + 16 * mt + 4 * g];
      stage(kn, cur ^ 1);
      asm volatile("s_waitcnt vmcnt(8)" ::: "memory");  // drain prev tile's 8 only
    } else {
      asm volatile("s_waitcnt vmcnt(0)" ::: "memory");
    }
    SCHED0();
    SBAR();

    // --- S^T = K·Q (3-way split) ---
    f32x4 s4[4];
    __builtin_amdgcn_s_setprio(1);
#pragma unroll
    for (int mt = 0; mt < 4; ++mt) {
      bf16x8 k0h = *(const bf16x8*)&KH[cur][(mt * 2 + 0) * 512 + lane * 8];
      bf16x8 k1h = *(const bf16x8*)&KH[cur][(mt * 2 + 1) * 512 + lane * 8];
      bf16x8 k0l = *(const bf16x8*)&KL[cur][(mt * 2 + 0) * 512 + lane * 8];
      bf16x8 k1l = *(const bf16x8*)&KL[cur][(mt * 2 + 1) * 512 + lane * 8];
      f32x4 sa = {};
      sa = mfma16(k0h, qh[0], sa);
      sa = mfma16(k1h, qh[1], sa);
      sa = mfma16(k0h, ql[0], sa);
      sa = mfma16(k1h, ql[1], sa);
      sa = mfma16(k0l, qh[0], sa);
      sa = mfma16(k1l, qh[1], sa);
      s4[mt] = sa;
    }
    __builtin_amdgcn_s_setprio(0);

#pragma unroll
    for (int mt = 0; mt < 4; ++mt)
#pragma unroll
      for (int r = 0; r < 4; ++r)
        s4[mt][r] = fmaf(s4[mt][r], 0.125f, (float)bmv[mt][r]);

    float tmax = -3.0e38f;
#pragma unroll
    for (int mt = 0; mt < 4; ++mt)
#pragma unroll
      for (int r = 0; r < 4; ++r) tmax = fmaxf(tmax, s4[mt][r]);
    tmax = fmaxf(tmax, __shfl_xor(tmax, 16));
    tmax = fmaxf(tmax, __shfl_xor(tmax, 32));
    if (!__all(tmax - m_run <= 8.0f)) {
      float mnew = fmaxf(m_run, tmax);
      float corr = __expf(m_run - mnew);
      l_run *= corr;
#pragma unroll
      for (int dt = 0; dt < 4; ++dt) aco[dt] *= corr;
      m_run = mnew;
    }
    float psum = 0.f;
    unsigned pk01[4], pk23[4];
#pragma unroll
    for (int mt = 0; mt < 4; ++mt) {
      float p0 = __expf(s4[mt][0] - m_run);
      float p1 = __expf(s4[mt][1] - m_run);
      float p2 = __expf(s4[mt][2] - m_run);
      float p3 = __expf(s4[mt][3] - m_run);
      psum += (p0 + p1) + (p2 + p3);
      pk01[mt] = pk2(p0, p1);
      pk23[mt] = pk2(p2, p3);
    }
    psum += __shfl_xor(psum, 16);
    psum += __shfl_xor(psum, 32);
    l_run += psum;

    // --- P -> B-frag via per-wave swizzled LDS scratch; PV per kss half ---
    __builtin_amdgcn_s_setprio(1);
#pragma unroll
    for (int kss = 0; kss < 2; ++kss) {
#pragma unroll
      for (int mh = 0; mh < 2; ++mh) {
        int mt = kss * 2 + mh;
        int phys = ((mh << 1) | (g >> 1)) ^ r3;
        uint2 w2;
        w2.x = pk01[mt];
        w2.y = pk23[mt];
        *(uint2*)&PS[psb + phys * 8 + (g & 1) * 4] = w2;
      }
      LGKM0();
      bf16x8 pf = *(const bf16x8*)&PS[psb + ((g ^ r3) << 3)];
#pragma unroll
      for (int dt = 0; dt < 4; ++dt) {
        bf16x8 vh = *(const bf16x8*)&VH[cur][(dt * 2 + kss) * 512 + lane * 8];
        bf16x8 vl = *(const bf16x8*)&VL[cur][(dt * 2 + kss) * 512 + lane * 8];
        aco[dt] = mfma16(vh, pf, aco[dt]);
        aco[dt] = mfma16(vl, pf, aco[dt]);
      }
    }
    __builtin_amdgcn_s_setprio(0);

    if (t + 1 < NT) {
#pragma unroll
      for (int mt = 0; mt < 4; ++mt) bmv[mt] = bmn[mt];
    }
    SBAR();
  }

  // epilogue: hi/lo bf16 output (feeds O-projection with zero in-kernel cvt)
  float inv = 1.0f / l_run;
#pragma unroll
  for (int dt = 0; dt < 4; ++dt) {
    f32x4 o = aco[dt] * inv;
    bf16x4 oh, ol;
#pragma unroll
    for (int r = 0; r < 4; ++r) {
      __bf16 hb = (__bf16)o[r];
      oh[r] = hb;
      ol[r] = (__bf16)(o[r] - (float)hb);
    }
    size_t off = ((size_t)b * TSEQ + qg) * DMODEL + h * HDIM + dt * 16 + 4 * g;
    *(bf16x4*)&Oh[off] = oh;
    *(bf16x4*)&Ol[off] = ol;
  }
}

extern "C" void kernel_launch(void* const* d_in, const int* in_sizes, int n_in,
                              void* d_out, int out_size, void* d_ws, size_t ws_size,
                              hipStream_t stream) {
  const float* query = (const float*)d_in[0];
  const float* key = (const float*)d_in[1];
  const float* value = (const float*)d_in[2];
  const unsigned char* kpm = (const unsigned char*)d_in[3];
  const float* amask = (const float*)d_in[4];
  const float* sf = (const float*)d_in[5];
  const float* Wq = (const float*)d_in[6];
  const float* bq = (const float*)d_in[7];
  const float* Wk = (const float*)d_in[8];
  const float* bk = (const float*)d_in[9];
  const float* Wv = (const float*)d_in[10];
  const float* bv = (const float*)d_in[11];
  const float* Wo = (const float*)d_in[12];
  const float* bo = (const float*)d_in[13];
  const float* alpha = (const float*)d_in[14];
  float* out = (float*)d_out;

  const size_t NEL = (size_t)2 * NHEAD * TSEQ * HDIM;  // 4,194,304 bf16 per array
  bf16_t* p = (bf16_t*)d_ws;
  bf16_t* Qh = p;                 // [0,  6NEL): QKV projections (attn operands)
  bf16_t* Ql = p + NEL;
  bf16_t* Kh = p + 2 * NEL;
  bf16_t* Kl = p + 3 * NEL;
  bf16_t* Vh = p + 4 * NEL;
  bf16_t* Vl = p + 5 * NEL;
  bf16_t* Oh = p + 6 * NEL;       // [6NEL, 8NEL): attn out hi/lo
  bf16_t* Ol = p + 7 * NEL;
  bf16_t* BMt = p + 8 * NEL;      // [8NEL, 10NEL): bias table (2 NEL)
  bf16_t* wsp = p + 10 * NEL;     // [10NEL, 12NEL): 4 weights x (hi+lo), 8 x WEL
  bf16_t* wqh = wsp + 0 * WEL, *wql = wsp + 1 * WEL;
  bf16_t* wkh = wsp + 2 * WEL, *wkl = wsp + 3 * WEL;
  bf16_t* wvh = wsp + 4 * WEL, *wvl = wsp + 5 * WEL;
  bf16_t* woh = wsp + 6 * WEL, *wol = wsp + 7 * WEL;
  // total ws use: 12 * NEL * 2B = 100.7 MiB

  presplit_w<<<dim3(WEL / (256 * 8), 4), dim3(256), 0, stream>>>(Wq, Wk, Wv, Wo, wsp);
  build_bias<<<dim3(4096), dim3(256), 0, stream>>>(amask, kpm, sf, alpha, BMt);

  dim3 gg(16, 32), gb(512);
  gemm_qkv<1><<<gg, gb, 0, stream>>>(query, wqh, wql, bq, Qh, Ql);
  gemm_qkv<1><<<gg, gb, 0, stream>>>(key, wkh, wkl, bk, Kh, Kl);
  gemm_qkv<2><<<gg, gb, 0, stream>>>(value, wvh, wvl, bv, Vh, Vl);
  dim3 ga(TSEQ / 128, NHEAD, 2);   // 512 blocks, 512 thr
  attn_mfma<<<ga, gb, 0, stream>>>(Qh, Ql, Kh, Kl, Vh, Vl, BMt, Oh, Ol);
  gemm_out<<<gg, gb, 0, stream>>>(Oh, Ol, woh, wol, bo, out);
}